// Round 9
// baseline (251.033 us; speedup 1.0000x reference)
//
#include <hip/hip_runtime.h>

#define TT    4096
#define U     32
#define CH    32                     // timesteps per chunk
#define NSEG  8                      // segments per batch (1 per chain wave)
#define SEGLEN (TT/NSEG)             // 512
#define WARMC 2                      // warm-up chunks = 64 steps
#define NCHK  (SEGLEN/CH + WARMC)    // 18 chunks per segment
#define TP    36                     // padded pxT row stride (floats)

#define CLOG2E 2.885390081777927f    // 2*log2(e)

typedef float v2f __attribute__((ext_vector_type(2)));

__global__ __launch_bounds__(768, 1)
void rnn_fused(const float* __restrict__ x,  const float* __restrict__ W1,
               const float* __restrict__ b1, const float* __restrict__ W2,
               const float* __restrict__ b2, const float* __restrict__ Wc,
               const float* __restrict__ bc, float* __restrict__ out, int B)
{
    __shared__ __align__(16) float xring[NSEG][2][CH][U];   // 64 KB
    __shared__ __align__(16) float pxT[NSEG][2][U][TP];     // 73.7 KB (holds px+1)
    __shared__ float part[NSEG];

    const int tid  = threadIdx.x;
    const int wid  = tid >> 6;          // 0..7 chain waves, 8..11 producer waves
    const int lane = tid & 63;
    const int v    = lane & 31;         // unit (upper half mirrors lower)
    const int h    = lane >> 5;
    const int b    = blockIdx.x;

    if (wid < NSEG) {
        // ============== chain wave: segment wid, SGPR broadcast ==============
        const int seg = wid;
        float w2s[U];
        #pragma unroll
        for (int i = 0; i < U; ++i) w2s[i] = W2[i*U + v] * CLOG2E;
        const float b2pre = b2[v] * CLOG2E;
        const float zm = (seg == 0) ? 0.f : 1.f;

        float state = 0.f, pool = 0.f;
        __syncthreads();                       // chunk-0 px ready

        #define RL(K) __uint_as_float(__builtin_amdgcn_readlane(__float_as_uint(state), (K)))
        for (int c = 0; c < NCHK; ++c) {
            if (c == WARMC) { state *= zm; pool = 0.f; }

            // fetch this chunk's px+1 row (32 values, off critical path)
            const float4* pxq = (const float4*)&pxT[seg][c & 1][v][0];
            float4 pq[8];
            #pragma unroll
            for (int q = 0; q < 8; ++q) pq[q] = pxq[q];

            #pragma unroll
            for (int s = 0; s < CH; ++s) {
                const float px1 = ((const float*)pq)[s];     // static after unroll
                float a0 = fmaf(RL(0), w2s[0], b2pre);
                float a1 = RL(1) * w2s[1];
                float a2 = RL(2) * w2s[2];
                float a3 = RL(3) * w2s[3];
                #pragma unroll
                for (int k = 4; k < 32; k += 4) {
                    a0 = fmaf(RL(k+0), w2s[k+0], a0);
                    a1 = fmaf(RL(k+1), w2s[k+1], a1);
                    a2 = fmaf(RL(k+2), w2s[k+2], a2);
                    a3 = fmaf(RL(k+3), w2s[k+3], a3);
                }
                float zs = (a0 + a1) + (a2 + a3);            // prescaled, +b2 folded
                float t  = __builtin_amdgcn_exp2f(zs);
                float r  = __builtin_amdgcn_rcpf(t + 1.0f);
                state = fmaf(-2.0f, r, px1);                 // px+1 + (tanh-1)
                pool += state;
            }
            __syncthreads();
        }
        #undef RL

        // per-segment partial of pooled dot with Wc
        float r = pool * Wc[v];
        r += __shfl_xor(r, 16);
        r += __shfl_xor(r, 8);
        r += __shfl_xor(r, 4);
        r += __shfl_xor(r, 2);
        r += __shfl_xor(r, 1);
        if (lane == 0) part[seg] = r;
        __syncthreads();
        if (tid == 0) {
            float acc = 0.f;
            #pragma unroll
            for (int i = 0; i < NSEG; ++i) acc += part[i];
            out[b] = acc * (1.0f / TT) + bc[0];
        }
    } else {
        // ============== producer wave p: segments 2p, 2p+1 ==============
        const int p  = wid - NSEG;           // 0..3
        const int sA = 2*p, sB = 2*p + 1;
        v2f w1p[16];
        #pragma unroll
        for (int i = 0; i < 16; ++i) {
            w1p[i][0] = W1[(2*i  )*U + v] * CLOG2E;
            w1p[i][1] = W1[(2*i+1)*U + v] * CLOG2E;
        }
        const float b1pre = b1[v] * CLOG2E;
        const float* xb = x + (size_t)b * TT * U;

        auto stage = [&](int seg, int cc) {    // stage chunk cc of segment seg
            const int t0 = seg*SEGLEN - WARMC*CH + cc*CH;
            float* dst = &xring[seg][cc & 1][0][0];
            #pragma unroll
            for (int q = 0; q < 4; ++q) {
                int row = t0 + q*8 + (lane >> 3);
                row = row < 0 ? 0 : (row >= TT ? TT-1 : row);   // clamp OOB
                const float* src = xb + (size_t)row*U + (lane & 7)*4;
                __builtin_amdgcn_global_load_lds(
                    (const __attribute__((address_space(1))) void*)src,
                    (__attribute__((address_space(3))) void*)(dst + q*256),
                    16, 0, 0);
            }
        };
        auto produce = [&](int seg, int cc) {  // px+1 for chunk cc into pxT
            const float* xs = &xring[seg][cc & 1][0][0];
            float* pxd = &pxT[seg][cc & 1][v][0];
            #pragma unroll 4
            for (int it = 0; it < CH/2; ++it) {
                const int tl = it*2 + h;                       // halves: even/odd rows
                const v2f* xr = (const v2f*)(xs + tl*U);       // 16 pairs (uniform/half)
                v2f a01 = __builtin_elementwise_fma(xr[0], w1p[0], (v2f){b1pre, 0.f});
                v2f a23 = xr[1] * w1p[1];
                a01 = __builtin_elementwise_fma(xr[2],  w1p[2],  a01);
                a23 = __builtin_elementwise_fma(xr[3],  w1p[3],  a23);
                a01 = __builtin_elementwise_fma(xr[4],  w1p[4],  a01);
                a23 = __builtin_elementwise_fma(xr[5],  w1p[5],  a23);
                a01 = __builtin_elementwise_fma(xr[6],  w1p[6],  a01);
                a23 = __builtin_elementwise_fma(xr[7],  w1p[7],  a23);
                a01 = __builtin_elementwise_fma(xr[8],  w1p[8],  a01);
                a23 = __builtin_elementwise_fma(xr[9],  w1p[9],  a23);
                a01 = __builtin_elementwise_fma(xr[10], w1p[10], a01);
                a23 = __builtin_elementwise_fma(xr[11], w1p[11], a23);
                a01 = __builtin_elementwise_fma(xr[12], w1p[12], a01);
                a23 = __builtin_elementwise_fma(xr[13], w1p[13], a23);
                a01 = __builtin_elementwise_fma(xr[14], w1p[14], a01);
                a23 = __builtin_elementwise_fma(xr[15], w1p[15], a23);
                float zs = (a01[0] + a01[1]) + (a23[0] + a23[1]);
                float t  = __builtin_amdgcn_exp2f(zs);
                float r  = __builtin_amdgcn_rcpf(t + 1.0f);
                pxd[tl] = fmaf(-2.0f, r, 2.0f);                // px + 1
            }
        };

        // prologue: stage chunks 0,1 of both segments; produce chunk 0
        stage(sA, 0); stage(sB, 0);
        stage(sA, 1); stage(sB, 1);
        asm volatile("s_waitcnt vmcnt(8)" ::: "memory");       // chunk-0 pair landed
        __builtin_amdgcn_sched_barrier(0);
        produce(sA, 0); produce(sB, 0);
        __syncthreads();

        for (int c = 0; c < NCHK; ++c) {
            stage(sA, c + 2);                  // dead slot (c+2)&1 (consumed)
            stage(sB, c + 2);
            asm volatile("s_waitcnt vmcnt(8)" ::: "memory");   // chunk c+1 pair landed
            __builtin_amdgcn_sched_barrier(0);
            if (c + 1 < NCHK) { produce(sA, c + 1); produce(sB, c + 1); }
            __syncthreads();
        }
        __syncthreads();                       // match chains' epilogue barrier
    }
}

extern "C" void kernel_launch(void* const* d_in, const int* in_sizes, int n_in,
                              void* d_out, int out_size, void* d_ws, size_t ws_size,
                              hipStream_t stream) {
    const float* x  = (const float*)d_in[0];
    const float* W1 = (const float*)d_in[1];
    const float* b1 = (const float*)d_in[2];
    const float* W2 = (const float*)d_in[3];
    const float* b2 = (const float*)d_in[4];
    const float* Wc = (const float*)d_in[5];
    const float* bc = (const float*)d_in[6];
    float* out = (float*)d_out;

    const int B = out_size;              // 256
    rnn_fused<<<B, 768, 0, stream>>>(x, W1, b1, W2, b2, Wc, bc, out, B);
}

// Round 11
// 123.949 us; speedup vs baseline: 2.0253x; 2.0253x over previous
//
#include <hip/hip_runtime.h>

#define TT     4096
#define U      32
#define NSEG   32
#define SEGLEN (TT/NSEG)            // 128
#define WARMC  2                    // 64 warm steps
#define TCH    32                   // steps per chunk
#define NCHK   (SEGLEN/TCH + WARMC) // 6
#define SSH    1164                 // ushorts per segment block (32*36 pad; 582 dwords -> 2-way banks)
#define BUFH   (NSEG*SSH)
#define CLOG2E 2.885390081777927f   // 2*log2(e)

typedef float  f32x16 __attribute__((ext_vector_type(16)));
typedef short  bf16x8 __attribute__((ext_vector_type(8)));

static __device__ __forceinline__ unsigned cvtpk(float a, float b) {
    unsigned r; asm("v_cvt_pk_bf16_f32 %0, %1, %2" : "=v"(r) : "v"(a), "v"(b)); return r;
}
static __device__ __forceinline__ float lo2f(unsigned u){ return __uint_as_float(u << 16); }
static __device__ __forceinline__ float hi2f(unsigned u){ return __uint_as_float(u & 0xffff0000u); }
static __device__ __forceinline__ bf16x8 pk8(unsigned a, unsigned b, unsigned c, unsigned d) {
    uint4 t; t.x = a; t.y = b; t.z = c; t.w = d;
    return __builtin_bit_cast(bf16x8, t);
}
#define MFMA(A,Bv,C) __builtin_amdgcn_mfma_f32_32x32x16_bf16((A),(Bv),(C),0,0,0)

__global__ __launch_bounds__(192, 1)
void rnn_fused(const float* __restrict__ x,  const float* __restrict__ W1,
               const float* __restrict__ b1, const float* __restrict__ W2,
               const float* __restrict__ b2, const float* __restrict__ Wc,
               const float* __restrict__ bc, float* __restrict__ out, int B)
{
    __shared__ __align__(16) unsigned short pxP[2*BUFH];   // px+1 as bf16, [buf][seg][t(36)][u]

    const int tid  = threadIdx.x;
    const int wid  = tid >> 6;          // 0: chain wave; 1,2: producer waves
    const int lane = tid & 63;
    const int c32  = lane & 31;
    const int h    = lane >> 5;
    const int b    = blockIdx.x;

    if (wid == 0) {
        // =================== MFMA chain wave: 32 segments ===================
        // A = W2^T prescaled (hi/lo bf16), 2 k-tiles. A row=c32, k=8h+j.
        bf16x8 Ah[2], Al[2];
        #pragma unroll
        for (int kt = 0; kt < 2; ++kt) {
            unsigned hi[4], lo[4];
            #pragma unroll
            for (int p = 0; p < 4; ++p) {
                float w0 = W2[(16*kt + 8*h + 2*p    )*U + c32] * CLOG2E;
                float w1 = W2[(16*kt + 8*h + 2*p + 1)*U + c32] * CLOG2E;
                hi[p] = cvtpk(w0, w1);
                lo[p] = cvtpk(w0 - lo2f(hi[p]), w1 - hi2f(hi[p]));
            }
            Ah[kt] = pk8(hi[0], hi[1], hi[2], hi[3]);
            Al[kt] = pk8(lo[0], lo[1], lo[2], lo[3]);
        }
        f32x16 biasC, pool, z16;
        float wcr[16];
        #pragma unroll
        for (int r = 0; r < 16; ++r) {
            const int row = (r & 3) + 8*(r >> 2) + 4*h;   // D row = output unit
            biasC[r] = b2[row] * CLOG2E;
            wcr[r]   = Wc[row];
            pool[r]  = 0.f;
            z16[r]   = 0.f;
        }
        const bf16x8 bz = {0,0,0,0,0,0,0,0};
        bf16x8 Bh0 = bz, Bh1 = bz, Bl0 = bz, Bl1 = bz;    // state fragments

        __syncthreads();                                  // chunk-0 px ready

        for (int c = 0; c < NCHK; ++c) {
            if (c == WARMC) {                             // warm/real boundary
                #pragma unroll
                for (int r = 0; r < 16; ++r) pool[r] = 0.f;
                if (c32 == 0) { Bh0 = bz; Bh1 = bz; Bl0 = bz; Bl1 = bz; }  // seg 0 starts at 0
            }
            const unsigned short* pr = pxP + (c & 1)*BUFH + c32*SSH + 4*h;
            for (int s = 0; s < TCH; ++s) {
                // px+1 for this step: 4 x b64, unit groups {0-3,8-11,16-19,24-27}+4h
                uint2 g0 = *(const uint2*)(pr + s*36);
                uint2 g1 = *(const uint2*)(pr + s*36 + 8);
                uint2 g2 = *(const uint2*)(pr + s*36 + 16);
                uint2 g3 = *(const uint2*)(pr + s*36 + 24);
                // z = W2^T y + b2 (prescaled): hi/lo split, two 3-deep mfma chains
                f32x16 a1 = MFMA(Ah[0], Bh0, biasC);
                a1 = MFMA(Ah[1], Bh1, a1);
                a1 = MFMA(Ah[0], Bl0, a1);
                f32x16 a2 = MFMA(Ah[1], Bl1, z16);
                a2 = MFMA(Al[0], Bh0, a2);
                a2 = MFMA(Al[1], Bh1, a2);
                float px1[16] = { lo2f(g0.x), hi2f(g0.x), lo2f(g0.y), hi2f(g0.y),
                                  lo2f(g1.x), hi2f(g1.x), lo2f(g1.y), hi2f(g1.y),
                                  lo2f(g2.x), hi2f(g2.x), lo2f(g2.y), hi2f(g2.y),
                                  lo2f(g3.x), hi2f(g3.x), lo2f(g3.y), hi2f(g3.y) };
                float y[16];
                #pragma unroll
                for (int r = 0; r < 16; ++r) {
                    float zz = a1[r] + a2[r];
                    float e  = __builtin_amdgcn_exp2f(zz);
                    float rc = __builtin_amdgcn_rcpf(e + 1.f);
                    y[r] = fmaf(-2.f, rc, px1[r]);        // px+1 + (tanh-1)
                    pool[r] += y[r];
                }
                // rebuild state fragments: pack, hi/lo, half-swap lane<->lane^32
                unsigned q[8], ql[8], sq[8], sql[8];
                #pragma unroll
                for (int p = 0; p < 8; ++p) {
                    q[p]  = cvtpk(y[2*p], y[2*p+1]);
                    ql[p] = cvtpk(y[2*p] - lo2f(q[p]), y[2*p+1] - hi2f(q[p]));
                }
                #pragma unroll
                for (int p = 0; p < 8; ++p) {
                    sq[p]  = (unsigned)__shfl_xor((int)q[p], 32);
                    sql[p] = (unsigned)__shfl_xor((int)ql[p], 32);
                }
                Bh0 = pk8(h ? sq[2]  : q[0],  h ? sq[3]  : q[1],  h ? q[2]  : sq[0],  h ? q[3]  : sq[1]);
                Bh1 = pk8(h ? sq[6]  : q[4],  h ? sq[7]  : q[5],  h ? q[6]  : sq[4],  h ? q[7]  : sq[5]);
                Bl0 = pk8(h ? sql[2] : ql[0], h ? sql[3] : ql[1], h ? ql[2] : sql[0], h ? ql[3] : sql[1]);
                Bl1 = pk8(h ? sql[6] : ql[4], h ? sql[7] : ql[5], h ? ql[6] : sql[4], h ? ql[7] : sql[5]);
            }
            __syncthreads();
        }

        // epilogue: out[b] = (sum over units,chains of pool*Wc)/T + bc
        float r = 0.f;
        #pragma unroll
        for (int rr = 0; rr < 16; ++rr) r = fmaf(pool[rr], wcr[rr], r);
        r += __shfl_xor(r, 32);
        r += __shfl_xor(r, 16);
        r += __shfl_xor(r, 8);
        r += __shfl_xor(r, 4);
        r += __shfl_xor(r, 2);
        r += __shfl_xor(r, 1);
        if (lane == 0) out[b] = r * (1.0f / TT) + bc[0];
    } else {
        // =================== producer waves: px = tanh(X W1 + b1) ===================
        const int pw = wid - 1;                            // segs pw*16 .. pw*16+15
        bf16x8 Wh[2], Wl[2];
        #pragma unroll
        for (int kt = 0; kt < 2; ++kt) {
            unsigned hi[4], lo[4];
            #pragma unroll
            for (int p = 0; p < 4; ++p) {
                float w0 = W1[(16*kt + 8*h + 2*p    )*U + c32] * CLOG2E;
                float w1 = W1[(16*kt + 8*h + 2*p + 1)*U + c32] * CLOG2E;
                hi[p] = cvtpk(w0, w1);
                lo[p] = cvtpk(w0 - lo2f(hi[p]), w1 - hi2f(hi[p]));
            }
            Wh[kt] = pk8(hi[0], hi[1], hi[2], hi[3]);
            Wl[kt] = pk8(lo[0], lo[1], lo[2], lo[3]);
        }
        f32x16 biasv, z16;
        {
            float bb = b1[c32] * CLOG2E;                   // D col = unit = c32
            #pragma unroll
            for (int r = 0; r < 16; ++r) { biasv[r] = bb; z16[r] = 0.f; }
        }
        const float* xb = x + (size_t)b * TT * U;

        auto LOAD = [&](float4* dst, int i, int cc) {      // A-frag of X for tile (seg,chunk)
            int row = (pw*16 + i)*SEGLEN - WARMC*TCH + cc*TCH + c32;
            row = row < 0 ? 0 : (row > TT-1 ? TT-1 : row);
            const float* rp = xb + (size_t)row*U + 8*h;
            dst[0] = *(const float4*)(rp);                 // kt0: units 8h+0..3
            dst[1] = *(const float4*)(rp + 4);             // kt0: units 8h+4..7
            dst[2] = *(const float4*)(rp + 16);            // kt1
            dst[3] = *(const float4*)(rp + 20);
        };
        auto COMP = [&](const float4* xr, int seg, int cc) {
            bf16x8 Xh[2], Xl[2];
            #pragma unroll
            for (int kt = 0; kt < 2; ++kt) {
                float f0 = xr[2*kt].x,   f1 = xr[2*kt].y,   f2 = xr[2*kt].z,   f3 = xr[2*kt].w;
                float f4 = xr[2*kt+1].x, f5 = xr[2*kt+1].y, f6 = xr[2*kt+1].z, f7 = xr[2*kt+1].w;
                unsigned h0 = cvtpk(f0, f1), h1 = cvtpk(f2, f3);
                unsigned h2 = cvtpk(f4, f5), h3 = cvtpk(f6, f7);
                unsigned l0 = cvtpk(f0 - lo2f(h0), f1 - hi2f(h0));
                unsigned l1 = cvtpk(f2 - lo2f(h1), f3 - hi2f(h1));
                unsigned l2 = cvtpk(f4 - lo2f(h2), f5 - hi2f(h2));
                unsigned l3 = cvtpk(f6 - lo2f(h3), f7 - hi2f(h3));
                Xh[kt] = pk8(h0, h1, h2, h3);
                Xl[kt] = pk8(l0, l1, l2, l3);
            }
            f32x16 a1 = MFMA(Xh[0], Wh[0], biasv);
            a1 = MFMA(Xh[1], Wh[1], a1);
            a1 = MFMA(Xh[0], Wl[0], a1);
            f32x16 a2 = MFMA(Xh[1], Wl[1], z16);
            a2 = MFMA(Xl[0], Wh[0], a2);
            a2 = MFMA(Xl[1], Wh[1], a2);
            unsigned short* pd = pxP + (cc & 1)*BUFH + seg*SSH + c32;
            #pragma unroll
            for (int r = 0; r < 16; ++r) {
                float zz = a1[r] + a2[r];
                float p1 = fmaf(-2.f, __builtin_amdgcn_rcpf(__builtin_amdgcn_exp2f(zz) + 1.f), 2.f);
                const int trow = (r & 3) + 8*(r >> 2) + 4*h;   // D row = time
                pd[trow*36] = (unsigned short)cvtpk(p1, p1);   // px+1 as bf16
            }
        };
        auto PRODUCE = [&](int cc) {
            float4 xr0[4], xr1[4], xr2[4], xr3[4];         // named 4-tile ring (static idx)
            LOAD(xr0, 0, cc); LOAD(xr1, 1, cc); LOAD(xr2, 2, cc); LOAD(xr3, 3, cc);
            __builtin_amdgcn_sched_barrier(0);
            #pragma unroll
            for (int i = 0; i < 16; i += 4) {
                COMP(xr0, pw*16 + i + 0, cc); if (i + 4 < 16) LOAD(xr0, i + 4, cc);
                __builtin_amdgcn_sched_barrier(0);
                COMP(xr1, pw*16 + i + 1, cc); if (i + 5 < 16) LOAD(xr1, i + 5, cc);
                __builtin_amdgcn_sched_barrier(0);
                COMP(xr2, pw*16 + i + 2, cc); if (i + 6 < 16) LOAD(xr2, i + 6, cc);
                __builtin_amdgcn_sched_barrier(0);
                COMP(xr3, pw*16 + i + 3, cc); if (i + 7 < 16) LOAD(xr3, i + 7, cc);
                __builtin_amdgcn_sched_barrier(0);
            }
        };

        PRODUCE(0);
        __syncthreads();
        for (int c = 0; c < NCHK; ++c) {
            if (c + 1 < NCHK) PRODUCE(c + 1);
            __syncthreads();
        }
    }
}

extern "C" void kernel_launch(void* const* d_in, const int* in_sizes, int n_in,
                              void* d_out, int out_size, void* d_ws, size_t ws_size,
                              hipStream_t stream) {
    const float* x  = (const float*)d_in[0];
    const float* W1 = (const float*)d_in[1];
    const float* b1 = (const float*)d_in[2];
    const float* W2 = (const float*)d_in[3];
    const float* b2 = (const float*)d_in[4];
    const float* Wc = (const float*)d_in[5];
    const float* bc = (const float*)d_in[6];
    float* out = (float*)d_out;

    const int B = out_size;              // 256
    rnn_fused<<<B, 192, 0, stream>>>(x, W1, b1, W2, b2, Wc, bc, out, B);
}

// Round 12
// 100.988 us; speedup vs baseline: 2.4858x; 1.2274x over previous
//
#include <hip/hip_runtime.h>

#define TT     4096
#define U      32
#define NSEG   32
#define SEGLEN (TT/NSEG)            // 128
#define WARMC  2                    // 64 warm steps
#define TCH    32                   // steps per chunk
#define NCHK   (SEGLEN/TCH + WARMC) // 6
#define SSH    1156                 // ushorts per segment block: 2312B; dword stride 578 == 2 mod 32 -> 2-way banks (free)
#define BUFH   (NSEG*SSH)
#define CLOG2E 2.885390081777927f   // 2*log2(e)

typedef float  f32x16 __attribute__((ext_vector_type(16)));
typedef short  bf16x8 __attribute__((ext_vector_type(8)));

static __device__ __forceinline__ unsigned cvtpk(float a, float b) {
    unsigned r; asm("v_cvt_pk_bf16_f32 %0, %1, %2" : "=v"(r) : "v"(a), "v"(b)); return r;
}
static __device__ __forceinline__ float lo2f(unsigned u){ return __uint_as_float(u << 16); }
static __device__ __forceinline__ float hi2f(unsigned u){ return __uint_as_float(u & 0xffff0000u); }
static __device__ __forceinline__ bf16x8 pk8(unsigned a, unsigned b, unsigned c, unsigned d) {
    uint4 t; t.x = a; t.y = b; t.z = c; t.w = d;
    return __builtin_bit_cast(bf16x8, t);
}
#define MFMA(A,Bv,C) __builtin_amdgcn_mfma_f32_32x32x16_bf16((A),(Bv),(C),0,0,0)

__global__ __launch_bounds__(192, 1)
void rnn_fused(const float* __restrict__ x,  const float* __restrict__ W1,
               const float* __restrict__ b1, const float* __restrict__ W2,
               const float* __restrict__ b2, const float* __restrict__ Wc,
               const float* __restrict__ bc, float* __restrict__ out, int B)
{
    __shared__ __align__(16) unsigned short pxP[2*BUFH];   // px+1 bf16, [buf][seg][t(36)][u]

    const int tid  = threadIdx.x;
    const int wid  = tid >> 6;          // 0: chain wave; 1,2: producer waves
    const int lane = tid & 63;
    const int c32  = lane & 31;
    const int h    = lane >> 5;
    const int b    = blockIdx.x;

    if (wid == 0) {
        // ============ MFMA chain wave: 32 segments, relabeled units ============
        // unit u = 16h + r lives at D reg r (half h) and at B slot (kt=(u>>3)&1, j=u&7).
        // A[row=c32][k=16kt+8h+j] = W2[16h+8kt+j, uo(c32)] * C
        const int uo = (c32 & 3) + 4*(c32 >> 3) + 16*((c32 >> 2) & 1);
        bf16x8 Ah[2], Al[2];
        #pragma unroll
        for (int kt = 0; kt < 2; ++kt) {
            unsigned hi[4], lo[4];
            #pragma unroll
            for (int p = 0; p < 4; ++p) {
                float w0 = W2[(16*h + 8*kt + 2*p    )*U + uo] * CLOG2E;
                float w1 = W2[(16*h + 8*kt + 2*p + 1)*U + uo] * CLOG2E;
                hi[p] = cvtpk(w0, w1);
                lo[p] = cvtpk(w0 - lo2f(hi[p]), w1 - hi2f(hi[p]));
            }
            Ah[kt] = pk8(hi[0], hi[1], hi[2], hi[3]);
            Al[kt] = pk8(lo[0], lo[1], lo[2], lo[3]);
        }
        f32x16 biasC, pool, z16;
        float wcr[16];
        #pragma unroll
        for (int r = 0; r < 16; ++r) {
            biasC[r] = b2[16*h + r] * CLOG2E;   // D reg r holds unit 16h+r
            wcr[r]   = Wc[16*h + r];
            pool[r]  = 0.f;
            z16[r]   = 0.f;
        }
        const bf16x8 bz = {0,0,0,0,0,0,0,0};
        bf16x8 Bh0 = bz, Bh1 = bz, Bl0 = bz, Bl1 = bz;

        __syncthreads();                                  // chunk-0 px ready

        for (int c = 0; c < NCHK; ++c) {
            if (c == WARMC) {                             // warm/real boundary
                #pragma unroll
                for (int r = 0; r < 16; ++r) pool[r] = 0.f;
                if (c32 == 0) { Bh0 = bz; Bh1 = bz; Bl0 = bz; Bl1 = bz; }  // seg 0 starts at 0
            }
            const unsigned short* pr = pxP + (c & 1)*BUFH + c32*SSH + 16*h;
            #pragma unroll 2
            for (int s = 0; s < TCH; ++s) {
                // px+1 for units 16h+0..15: 4x b64, contiguous
                uint2 g0 = *(const uint2*)(pr + s*36);
                uint2 g1 = *(const uint2*)(pr + s*36 + 4);
                uint2 g2 = *(const uint2*)(pr + s*36 + 8);
                uint2 g3 = *(const uint2*)(pr + s*36 + 12);
                // z = W2^T y + b2 (prescaled), hi/lo split: two 3-deep mfma chains
                f32x16 a1 = MFMA(Ah[0], Bh0, biasC);
                a1 = MFMA(Ah[1], Bh1, a1);
                a1 = MFMA(Ah[0], Bl0, a1);
                f32x16 a2 = MFMA(Ah[1], Bl1, z16);
                a2 = MFMA(Al[0], Bh0, a2);
                a2 = MFMA(Al[1], Bh1, a2);
                float px1[16] = { lo2f(g0.x), hi2f(g0.x), lo2f(g0.y), hi2f(g0.y),
                                  lo2f(g1.x), hi2f(g1.x), lo2f(g1.y), hi2f(g1.y),
                                  lo2f(g2.x), hi2f(g2.x), lo2f(g2.y), hi2f(g2.y),
                                  lo2f(g3.x), hi2f(g3.x), lo2f(g3.y), hi2f(g3.y) };
                float y[16];
                #pragma unroll
                for (int r = 0; r < 16; ++r) {
                    float zz = a1[r] + a2[r];
                    float e  = __builtin_amdgcn_exp2f(zz);
                    float rc = __builtin_amdgcn_rcpf(e + 1.f);
                    y[r] = fmaf(-2.f, rc, px1[r]);        // px+1 + (tanh-1)
                    pool[r] += y[r];
                }
                // rebuild state fragments in place: units 0..7 -> kt0, 8..15 -> kt1 (per half)
                unsigned q[8], ql[8];
                #pragma unroll
                for (int p = 0; p < 8; ++p) {
                    q[p]  = cvtpk(y[2*p], y[2*p+1]);
                    ql[p] = cvtpk(y[2*p] - lo2f(q[p]), y[2*p+1] - hi2f(q[p]));
                }
                Bh0 = pk8(q[0],  q[1],  q[2],  q[3]);
                Bh1 = pk8(q[4],  q[5],  q[6],  q[7]);
                Bl0 = pk8(ql[0], ql[1], ql[2], ql[3]);
                Bl1 = pk8(ql[4], ql[5], ql[6], ql[7]);
            }
            __syncthreads();
        }

        // epilogue: out[b] = (sum over units,segments of pool*Wc)/T + bc
        float r = 0.f;
        #pragma unroll
        for (int rr = 0; rr < 16; ++rr) r = fmaf(pool[rr], wcr[rr], r);
        r += __shfl_xor(r, 32);
        r += __shfl_xor(r, 16);
        r += __shfl_xor(r, 8);
        r += __shfl_xor(r, 4);
        r += __shfl_xor(r, 2);
        r += __shfl_xor(r, 1);
        if (lane == 0) out[b] = r * (1.0f / TT) + bc[0];
    } else {
        // =================== producer waves: px = tanh(X W1 + b1) ===================
        const int pw = wid - 1;                            // segs pw*16 .. pw*16+15
        bf16x8 Wh[2], Wl[2];
        #pragma unroll
        for (int kt = 0; kt < 2; ++kt) {
            unsigned hi[4], lo[4];
            #pragma unroll
            for (int p = 0; p < 4; ++p) {
                float w0 = W1[(16*kt + 8*h + 2*p    )*U + c32] * CLOG2E;
                float w1 = W1[(16*kt + 8*h + 2*p + 1)*U + c32] * CLOG2E;
                hi[p] = cvtpk(w0, w1);
                lo[p] = cvtpk(w0 - lo2f(hi[p]), w1 - hi2f(hi[p]));
            }
            Wh[kt] = pk8(hi[0], hi[1], hi[2], hi[3]);
            Wl[kt] = pk8(lo[0], lo[1], lo[2], lo[3]);
        }
        f32x16 biasv, z16;
        {
            float bb = b1[c32] * CLOG2E;                   // D col = unit = c32
            #pragma unroll
            for (int r = 0; r < 16; ++r) { biasv[r] = bb; z16[r] = 0.f; }
        }
        const float* xb = x + (size_t)b * TT * U;

        auto LOAD = [&](float4* dst, int i, int cc) {      // A-frag of X for tile (seg,chunk)
            int row = (pw*16 + i)*SEGLEN - WARMC*TCH + cc*TCH + c32;
            row = row < 0 ? 0 : (row > TT-1 ? TT-1 : row);
            const float* rp = xb + (size_t)row*U + 8*h;
            dst[0] = *(const float4*)(rp);                 // kt0: units 8h+0..3
            dst[1] = *(const float4*)(rp + 4);             // kt0: units 8h+4..7
            dst[2] = *(const float4*)(rp + 16);            // kt1
            dst[3] = *(const float4*)(rp + 20);
        };
        auto COMP = [&](const float4* xr, int seg, int cc) {
            bf16x8 Xh[2], Xl[2];
            #pragma unroll
            for (int kt = 0; kt < 2; ++kt) {
                float f0 = xr[2*kt].x,   f1 = xr[2*kt].y,   f2 = xr[2*kt].z,   f3 = xr[2*kt].w;
                float f4 = xr[2*kt+1].x, f5 = xr[2*kt+1].y, f6 = xr[2*kt+1].z, f7 = xr[2*kt+1].w;
                unsigned h0 = cvtpk(f0, f1), h1 = cvtpk(f2, f3);
                unsigned h2 = cvtpk(f4, f5), h3 = cvtpk(f6, f7);
                unsigned l0 = cvtpk(f0 - lo2f(h0), f1 - hi2f(h0));
                unsigned l1 = cvtpk(f2 - lo2f(h1), f3 - hi2f(h1));
                unsigned l2 = cvtpk(f4 - lo2f(h2), f5 - hi2f(h2));
                unsigned l3 = cvtpk(f6 - lo2f(h3), f7 - hi2f(h3));
                Xh[kt] = pk8(h0, h1, h2, h3);
                Xl[kt] = pk8(l0, l1, l2, l3);
            }
            f32x16 a1 = MFMA(Xh[0], Wh[0], biasv);
            a1 = MFMA(Xh[1], Wh[1], a1);
            a1 = MFMA(Xh[0], Wl[0], a1);
            f32x16 a2 = MFMA(Xh[1], Wl[1], z16);
            a2 = MFMA(Xl[0], Wh[0], a2);
            a2 = MFMA(Xl[1], Wh[1], a2);
            unsigned short* pd = pxP + (cc & 1)*BUFH + seg*SSH + c32;
            #pragma unroll
            for (int r = 0; r < 16; ++r) {
                float zz = a1[r] + a2[r];
                float p1 = fmaf(-2.f, __builtin_amdgcn_rcpf(__builtin_amdgcn_exp2f(zz) + 1.f), 2.f);
                const int trow = (r & 3) + 8*(r >> 2) + 4*h;   // D row = time
                pd[trow*36] = (unsigned short)cvtpk(p1, p1);   // px+1 as bf16
            }
        };
        auto PRODUCE = [&](int cc) {
            float4 xr0[4], xr1[4], xr2[4], xr3[4];         // named 4-tile ring (static idx)
            LOAD(xr0, 0, cc); LOAD(xr1, 1, cc); LOAD(xr2, 2, cc); LOAD(xr3, 3, cc);
            __builtin_amdgcn_sched_barrier(0);
            #pragma unroll
            for (int i = 0; i < 16; i += 4) {
                COMP(xr0, pw*16 + i + 0, cc); if (i + 4 < 16) LOAD(xr0, i + 4, cc);
                __builtin_amdgcn_sched_barrier(0);
                COMP(xr1, pw*16 + i + 1, cc); if (i + 5 < 16) LOAD(xr1, i + 5, cc);
                __builtin_amdgcn_sched_barrier(0);
                COMP(xr2, pw*16 + i + 2, cc); if (i + 6 < 16) LOAD(xr2, i + 6, cc);
                __builtin_amdgcn_sched_barrier(0);
                COMP(xr3, pw*16 + i + 3, cc); if (i + 7 < 16) LOAD(xr3, i + 7, cc);
                __builtin_amdgcn_sched_barrier(0);
            }
        };

        PRODUCE(0);
        __syncthreads();
        for (int c = 0; c < NCHK; ++c) {
            if (c + 1 < NCHK) PRODUCE(c + 1);
            __syncthreads();
        }
    }
}

extern "C" void kernel_launch(void* const* d_in, const int* in_sizes, int n_in,
                              void* d_out, int out_size, void* d_ws, size_t ws_size,
                              hipStream_t stream) {
    const float* x  = (const float*)d_in[0];
    const float* W1 = (const float*)d_in[1];
    const float* b1 = (const float*)d_in[2];
    const float* W2 = (const float*)d_in[3];
    const float* b2 = (const float*)d_in[4];
    const float* Wc = (const float*)d_in[5];
    const float* bc = (const float*)d_in[6];
    float* out = (float*)d_out;

    const int B = out_size;              // 256
    rnn_fused<<<B, 192, 0, stream>>>(x, W1, b1, W2, b2, Wc, bc, out, B);
}